// Round 12
// baseline (275.356 us; speedup 1.0000x reference)
//
#include <hip/hip_runtime.h>

// Problem constants (fixed by setup_inputs)
static constexpr int V  = 5;
static constexpr int B  = 2;
static constexpr int C  = 32;
static constexpr int H  = 256;
static constexpr int W  = 320;
static constexpr int CN = 4;
static constexpr int HW = H * W;
static constexpr int CG = 8;   // channels per group (per wave)
static constexpr int NG = 4;   // groups per block
static constexpr int XT = W / 64;        // 5 x-tiles
static constexpr int NBLK = XT * H * B;  // 2560 fused blocks

static constexpr size_t PARAMS_OFF = 0;

typedef float f32x2 __attribute__((ext_vector_type(2)));
typedef float f32x4 __attribute__((ext_vector_type(4)));

// Alignment-safe paired load (global: dwordx2; LDS: ds_read2_b32)
__device__ __forceinline__ f32x2 ld2(const float* p) {
    f32x2 v;
    __builtin_memcpy(&v, p, sizeof(f32x2));
    return v;
}

// ---------------------------------------------------------------------------
// Setup: per (b, src view i=1..4) compute proj = M_i @ inv(M_0) -> 12 floats
// ---------------------------------------------------------------------------
__global__ void setup_proj_kernel(const float* __restrict__ pm, float* __restrict__ params) {
    int b = threadIdx.x;
    if (b >= B) return;

    float M[V][16];
    for (int v = 0; v < V; ++v) {
        const float* E  = pm + ((size_t)(b * V + v) * 2 + 0) * 16;
        const float* Km = pm + ((size_t)(b * V + v) * 2 + 1) * 16;
        for (int r = 0; r < 3; ++r)
            for (int c = 0; c < 4; ++c) {
                float s = 0.f;
                for (int k = 0; k < 3; ++k) s += Km[r * 4 + k] * E[k * 4 + c];
                M[v][r * 4 + c] = s;
            }
        for (int c = 0; c < 4; ++c) M[v][12 + c] = E[12 + c];
    }

    float A[9], bb[3];
    for (int r = 0; r < 3; ++r) {
        for (int c = 0; c < 3; ++c) A[r * 3 + c] = M[0][r * 4 + c];
        bb[r] = M[0][r * 4 + 3];
    }
    float det = A[0] * (A[4] * A[8] - A[5] * A[7])
              - A[1] * (A[3] * A[8] - A[5] * A[6])
              + A[2] * (A[3] * A[7] - A[4] * A[6]);
    float id = 1.f / det;
    float Ai[9];
    Ai[0] = (A[4] * A[8] - A[5] * A[7]) * id;
    Ai[1] = (A[2] * A[7] - A[1] * A[8]) * id;
    Ai[2] = (A[1] * A[5] - A[2] * A[4]) * id;
    Ai[3] = (A[5] * A[6] - A[3] * A[8]) * id;
    Ai[4] = (A[0] * A[8] - A[2] * A[6]) * id;
    Ai[5] = (A[2] * A[3] - A[0] * A[5]) * id;
    Ai[6] = (A[3] * A[7] - A[4] * A[6]) * id;
    Ai[7] = (A[1] * A[6] - A[0] * A[7]) * id;
    Ai[8] = (A[0] * A[4] - A[1] * A[3]) * id;
    float bi[3];
    for (int r = 0; r < 3; ++r)
        bi[r] = -(Ai[r * 3 + 0] * bb[0] + Ai[r * 3 + 1] * bb[1] + Ai[r * 3 + 2] * bb[2]);

    float Minv[16];
    for (int r = 0; r < 3; ++r) {
        for (int c = 0; c < 3; ++c) Minv[r * 4 + c] = Ai[r * 3 + c];
        Minv[r * 4 + 3] = bi[r];
    }
    Minv[12] = 0.f; Minv[13] = 0.f; Minv[14] = 0.f; Minv[15] = 1.f;

    for (int v = 1; v < V; ++v) {
        float* dst = params + (size_t)(b * (V - 1) + (v - 1)) * 12;
        for (int r = 0; r < 3; ++r)
            for (int c = 0; c < 4; ++c) {
                float s = 0.f;
                for (int k = 0; k < 4; ++k) s += M[v][r * 4 + k] * Minv[k * 4 + c];
                dst[r * 4 + c] = s;
            }
    }
}

// ---------------------------------------------------------------------------
// Fused kernel v12 = v10 dual-pipe, rebalanced 5 LDS / 3 global.
// v10 (128us) proved the two gather pipes overlap; v11's prefetch-ahead
// regressed (135us, same VGPR/occ/conflicts) -> reverted. Per-CU budget from
// measured constants (r2: scattered ld2 ~33cyc TA-bound): v10's global half
// ~70us vs LDS half ~40-50us -> TA pipe still binding at a 4/4 split.
// Balance point ~5 LDS : 3 global (3x216 ~ 5x125 cyc/channel).
// Five phases per view: each stages+gathers LDS channel q (0..4); phases
// 0-2 additionally carry the global scattered batch for channels 5-7.
// Same-phase Rs issue->commit (v10's measured-fastest pattern); statically
// unrolled so rf[] is static; no barriers in the loop (stage[g] wave-private,
// same-wave DS in-order); register discipline unchanged.
// ---------------------------------------------------------------------------
__global__ __launch_bounds__(256) void fused_kernel(
    const float* __restrict__ depth_values,   // (B,1,H,W)
    const float* __restrict__ features,       // (V,B,C,H,W)
    const float* __restrict__ depth_interval, // (B,1,H,W)
    const float* __restrict__ view_weights,   // (B,V-1,H,W)
    const float* __restrict__ params,         // (B,V-1,12)
    float* __restrict__ out)                  // (B,C*CN,H,W)
{
    const int tid = threadIdx.x;
    const int p   = tid & 63;
    const int g   = tid >> 6;

    // row-sharing XCD swizzle (bijective)
    const int d   = blockIdx.x;
    const int u   = d >> 3;             // 0..319
    const int r8  = d & 7;
    const int xt  = u % XT;
    const int rid = r8 * 64 + u / XT;   // 0..511
    const int y   = rid & (H - 1);
    const int b   = rid >> 8;

    const int x   = xt * 64 + p;
    const int pix = y * W + x;

    __shared__ float sp4[48];            // 4 views x 12 params
    __shared__ float stage[NG][960];     // per-group: 1ch x 3 rows x 320 (15.6 KB)
    float* const sredp = &stage[0][0];   // aliased post-gather: [NG][CN][64]
    float* const simp  = &stage[0][0] + 1024;  // aliased post-gather: [CN][64]

    if (tid < 48) sp4[tid] = params[(size_t)b * 48 + tid];
    __syncthreads();

    const float invd = 1.f / depth_values[(size_t)b * HW + pix];
    const float itv  = depth_interval[(size_t)b * HW + pix];
    const float low  = invd - (CN * 0.5f) * itv;
    const float step = (CN * itv) / (float)(CN - 1);
    float dep[CN];
#pragma unroll
    for (int k = 0; k < CN; ++k) dep[k] = 1.f / (low + (float)k * step);

    // prefetch all 4 view weights (off the per-view critical chain)
    float vws[V - 1];
#pragma unroll
    for (int i = 0; i < V - 1; ++i)
        vws[i] = view_weights[((size_t)b * (V - 1) + i) * HW + pix];
    float wsum = 1e-5f;
#pragma unroll
    for (int i = 0; i < V - 1; ++i) wsum += vws[i];

    // this group's reference channels: read once -> NT load
    const float* refp = features + ((size_t)b * C + g * CG) * HW + pix;
    float rf[CG];
#pragma unroll
    for (int c = 0; c < CG; ++c) rf[c] = __builtin_nontemporal_load(refp + (size_t)c * HW);

    // per-lane staging offsets: slot = it*64+p covers 240 f32x4 = 960 floats
    // = 3 rows x 320 of ONE channel. Valid: slot<240 <=> it<3 || p<48.
    int soff[4];
#pragma unroll
    for (int it = 0; it < 4; ++it) {
        const int f   = (it * 64 + p) * 4;
        const int j   = (f >= 640) ? 2 : ((f >= 320) ? 1 : 0);
        const int col = f - j * 320;
        const int row = min(max(y - 1 + j, 0), H - 1);
        soff[it] = row * W + col;
    }

    // scalar row bases for the global-gather half (clamped)
    const int rbm = max(y - 1, 0) * W;      // row y-1
    const int rb0 = y * W;                  // row y
    const int rbp = min(y + 1, H - 1) * W;  // row y+1

    const size_t VSTRIDE = (size_t)B * C * HW;
    const float* src = features + ((size_t)(B + b) * C + g * CG) * HW;  // view iv=0

    const float fx = (float)x, fy = (float)y;
    float volsum[CN] = {0.f, 0.f, 0.f, 0.f};

    for (int iv = 0; iv < V - 1; ++iv, src += VSTRIDE) {
        const float* spv = &sp4[iv * 12];
        const float rx = spv[0] * fx + spv[1] * fy + spv[2];
        const float ry = spv[4] * fx + spv[5] * fy + spv[6];
        const float rz = spv[8] * fx + spv[9] * fy + spv[10];
        const float tx = spv[3], ty = spv[7], tz = spv[11];

        const float scale = vws[iv] * (1.f / (float)C);

        int   o0[CN];
        float wA0[CN], wB0[CN], wA1[CN], wB1[CN];
#pragma unroll
        for (int k = 0; k < CN; ++k) {
            const float dd = dep[k];
            const float px = rx * dd + tx;
            const float py = ry * dd + ty;
            const float pz = rz * dd + tz;
            const float iz = 1.f / pz;
            const float gx = px * iz;
            const float gy = py * iz;

            const float x0f = floorf(gx), y0f = floorf(gy);
            const float wx1 = gx - x0f, wy1 = gy - y0f;
            const float wx0 = 1.f - wx1, wy0 = 1.f - wy1;
            const int x0 = (int)x0f, y0 = (int)y0f;
            const int x1 = x0 + 1, y1 = y0 + 1;

            const bool vx0 = (x0 >= 0) && (x0 <= W - 1);
            const bool vx1 = (x1 >= 0) && (x1 <= W - 1);
            const bool vy0 = (y0 >= 0) && (y0 <= H - 1);
            const bool vy1 = (y1 >= 0) && (y1 <= H - 1);

            const int bx = min(max(x0, 0), W - 2);
            const int s  = x0 - bx;   // {-1, 0, 1} (else all weights 0)

            const float w00 = wx0 * wy0 * ((vx0 && vy0) ? scale : 0.f);
            const float w10 = wx1 * wy0 * ((vx1 && vy0) ? scale : 0.f);
            const float w01 = wx0 * wy1 * ((vx0 && vy1) ? scale : 0.f);
            const float w11 = wx1 * wy1 * ((vx1 && vy1) ? scale : 0.f);

            wA0[k] = (s == 0) ? w00 : ((s == -1) ? w10 : 0.f);
            wB0[k] = (s == 0) ? w10 : ((s == 1) ? w00 : 0.f);
            wA1[k] = (s == 0) ? w01 : ((s == -1) ? w11 : 0.f);
            wB1[k] = (s == 0) ? w11 : ((s == 1) ? w01 : 0.f);

            // staged-buffer offset; fast iff y0 in {y-1, y} <=> 0<=o0<=638
            o0[k] = (y0 - y + 1) * 320 + bx;
        }

        bool okrow = true;
#pragma unroll
        for (int k = 0; k < CN; ++k)
            okrow = okrow && ((unsigned)o0[k] <= 638u);

        if (__all(okrow)) {
            // global-gather addresses for the direct half (derived from o0;
            // selects only, no runtime-indexed arrays)
            int ga0[CN], ga1[CN];
#pragma unroll
            for (int k = 0; k < CN; ++k) {
                const bool j1  = o0[k] >= 320;
                const int  col = o0[k] - (j1 ? 320 : 0);
                ga0[k] = (j1 ? rb0 : rbm) + col;   // bilinear row 0 (clamped)
                ga1[k] = (j1 ? rbp : rb0) + col;   // bilinear row 1 (clamped)
            }

            // 5 phases: LDS channel q (0..4); phases 0-2 also carry the
            // global scattered batch for channel q+5.
#pragma unroll
            for (int q = 0; q < 5; ++q) {
                // (1) issue stage loads for LDS channel q
                const float* sc = src + (size_t)q * HW;
                f32x4 Rs0, Rs1, Rs2, Rs3;
                Rs0 = *(const f32x4*)(sc + soff[0]);
                Rs1 = *(const f32x4*)(sc + soff[1]);
                Rs2 = *(const f32x4*)(sc + soff[2]);
                if (p < 48) Rs3 = *(const f32x4*)(sc + soff[3]);

                // (2) issue global scattered batch for channel q+5 (q<3)
                f32x2 GA[CN], GB[CN];
                if (q < 3) {
                    const float* gc = src + (size_t)(q + 5) * HW;
#pragma unroll
                    for (int k = 0; k < CN; ++k) {
                        GA[k] = ld2(gc + ga0[k]);
                        GB[k] = ld2(gc + ga1[k]);
                    }
                }

                // (3) commit stage to LDS (waits only on Rs*)
                *(f32x4*)&stage[g][(0 * 64 + p) * 4] = Rs0;
                *(f32x4*)&stage[g][(1 * 64 + p) * 4] = Rs1;
                *(f32x4*)&stage[g][(2 * 64 + p) * 4] = Rs2;
                if (p < 48) *(f32x4*)&stage[g][(3 * 64 + p) * 4] = Rs3;

                // (4) gather LDS channel q (same-wave DS in-order)
                {
                    const float rfc = rf[q];
                    const float* L = &stage[g][0];
#pragma unroll
                    for (int k = 0; k < CN; ++k) {
                        const f32x2 a  = ld2(L + o0[k]);
                        const f32x2 b2 = ld2(L + o0[k] + 320);
                        float t = wA0[k] * a.x;
                        t = fmaf(wB0[k], a.y, t);
                        t = fmaf(wA1[k], b2.x, t);
                        t = fmaf(wB1[k], b2.y, t);
                        volsum[k] = fmaf(rfc, t, volsum[k]);
                    }
                }

                // (5) consume the global batch for channel q+5 (q<3)
                if (q < 3) {
                    const float rfc = rf[q + 5];
#pragma unroll
                    for (int k = 0; k < CN; ++k) {
                        float t = wA0[k] * GA[k].x;
                        t = fmaf(wB0[k], GA[k].y, t);
                        t = fmaf(wA1[k], GB[k].x, t);
                        t = fmaf(wB1[k], GB[k].y, t);
                        volsum[k] = fmaf(rfc, t, volsum[k]);
                    }
                }
            }
        } else {
            // GENERIC fallback (cold): compact global gather; recompute rows.
#pragma unroll 1
            for (int k = 0; k < CN; ++k) {
                const float dd = dep[k];
                const float gy = (ry * dd + ty) / (rz * dd + tz);
                const int   y0 = (int)floorf(gy);
                const int  cy0 = min(max(y0,     0), H - 1);
                const int  cy1 = min(max(y0 + 1, 0), H - 1);
                const int   bx = o0[k] - (y0 - y + 1) * 320;   // recover bx
                const int  ib0 = cy0 * W + bx;
                const int  ib1 = cy1 * W + bx;
#pragma unroll 1
                for (int c = 0; c < CG; ++c) {
                    const float* fc  = src + (size_t)c * HW;
                    const f32x2 a   = ld2(fc + ib0);
                    const f32x2 bb2 = ld2(fc + ib1);
                    float t = wA0[k] * a.x;
                    t = fmaf(wB0[k], a.y, t);
                    t = fmaf(wA1[k], bb2.x, t);
                    t = fmaf(wB1[k], bb2.y, t);
                    volsum[k] = fmaf(rf[c], t, volsum[k]);
                }
            }
        }
    }

    // cross-group reduce + normalize; sred/sim alias the (now dead) stage buf.
    __syncthreads();
#pragma unroll
    for (int k = 0; k < CN; ++k) sredp[(g * CN + k) * 64 + p] = volsum[k];
    __syncthreads();

    {
        const int k = g;   // NG == CN: group g owns depth k = g
        const float s = sredp[(0 * CN + k) * 64 + p] + sredp[(1 * CN + k) * 64 + p]
                      + sredp[(2 * CN + k) * 64 + p] + sredp[(3 * CN + k) * 64 + p];
        simp[k * 64 + p] = s * (1.f / wsum);
    }
    __syncthreads();

    // broadcast-write 128 planes x 64 px with regular cached stores.
    {
        const int quad = tid & 15;
        const int pc   = tid >> 4;
        float* op = out + (size_t)b * C * CN * HW + y * W + xt * 64 + quad * 4;
#pragma unroll
        for (int j = 0; j < 8; ++j) {
            const int plane = pc * 8 + j;          // 0..127, each exactly once
            const int k     = plane & 3;
            const f32x4 v   = *(const f32x4*)&simp[k * 64 + quad * 4];
            *(f32x4*)(op + (size_t)plane * HW) = v;
        }
    }
}

extern "C" void kernel_launch(void* const* d_in, const int* in_sizes, int n_in,
                              void* d_out, int out_size, void* d_ws, size_t ws_size,
                              hipStream_t stream) {
    const float* depth_values   = (const float*)d_in[0];
    const float* features       = (const float*)d_in[1];
    const float* proj_matrices  = (const float*)d_in[2];
    const float* depth_interval = (const float*)d_in[3];
    const float* view_weights   = (const float*)d_in[7];
    float* out    = (float*)d_out;
    float* params = (float*)d_ws + PARAMS_OFF;    // 96 floats

    setup_proj_kernel<<<1, B, 0, stream>>>(proj_matrices, params);

    fused_kernel<<<NBLK, 256, 0, stream>>>(depth_values, features, depth_interval,
                                           view_weights, params, out);
}